// Round 2
// baseline (3468.525 us; speedup 1.0000x reference)
//
#include <hip/hip_runtime.h>

#define NN 100000
#define NE 300000
#define DD 128
#define ND 12800000LL   // NN*DD
#define NBLK1 3125      // NN/32

// Build Wcat[640][128], bias1[128], W2cat[256][128], bias2[128] in fp32.
// Wcat row k, col f layouts chosen so GEMM reads are contiguous in f.
__global__ __launch_bounds__(256) void prep_weights(
    const float* __restrict__ Wl0, const float* __restrict__ bl0, const float* __restrict__ Wr0,
    const float* __restrict__ Wl1, const float* __restrict__ bl1, const float* __restrict__ Wr1,
    const float* __restrict__ Wl2, const float* __restrict__ bl2, const float* __restrict__ Wr2,
    const float* __restrict__ Wla, const float* __restrict__ bla, const float* __restrict__ Wra,
    const float* __restrict__ Wf,  const float* __restrict__ bfv, const float* __restrict__ Wrf,
    const float* __restrict__ wt,
    float* __restrict__ Wcat, float* __restrict__ bias1,
    float* __restrict__ W2cat, float* __restrict__ bias2) {
    int idx = blockIdx.x * 256 + threadIdx.x;
    float w0 = wt[0], w1 = wt[1], w2 = wt[2];
    if (idx < 81920) {
        int k = idx >> 7, f = idx & 127;
        float v;
        if (k < 128)      v = w0 * Wl0[f * 128 + k];
        else if (k < 256) v = w1 * Wl1[f * 128 + (k - 128)];
        else if (k < 384) v = w2 * Wl2[f * 128 + (k - 256)];
        else if (k < 512) v = Wla[f * 128 + (k - 384)];
        else {
            int kk = k - 512;
            v = w0 * Wr0[f * 128 + kk] + w1 * Wr1[f * 128 + kk] +
                w2 * Wr2[f * 128 + kk] + Wra[f * 128 + kk];
        }
        Wcat[idx] = v;
    } else if (idx < 81920 + 32768) {
        int j = idx - 81920;
        int k = j >> 7, f = j & 127;
        W2cat[j] = (k < 128) ? Wf[f * 128 + k] : Wrf[f * 128 + (k - 128)];
    } else if (idx < 81920 + 32768 + 128) {
        int f = idx - (81920 + 32768);
        bias1[f] = w0 * bl0[f] + w1 * bl1[f] + w2 * bl2[f] + bla[f];
        bias2[f] = bfv[f];
    }
}

// Stage A: scatter feat rows into agg0/1/2 (fp32) and bump cnt0/1/2. Wave per edge.
__global__ __launch_bounds__(256) void scatterA(
    const float* __restrict__ feat,
    const int* __restrict__ e0, const int* __restrict__ e1, const int* __restrict__ e2,
    float* __restrict__ agg, float* __restrict__ cnt) {
    int gid = blockIdx.x * 256 + threadIdx.x;
    int wid = gid >> 6, lane = threadIdx.x & 63;
    int nw = (gridDim.x * 256) >> 6;
    for (int e = wid; e < 3 * NE; e += nw) {
        int t, i;
        if (e < NE) { t = 0; i = e; }
        else if (e < 2 * NE) { t = 1; i = e - NE; }
        else { t = 2; i = e - 2 * NE; }
        const int* ep = (t == 0) ? e0 : ((t == 1) ? e1 : e2);
        int src = ep[i], dst = ep[NE + i];
        float2 v = *(const float2*)(feat + (size_t)src * DD + 2 * lane);
        float* ag = agg + (size_t)t * ND + (size_t)dst * DD + 2 * lane;
        unsafeAtomicAdd(ag, v.x);
        unsafeAtomicAdd(ag + 1, v.y);
        if (lane == 0) unsafeAtomicAdd(cnt + t * NN + dst, 1.0f);
    }
}

// Stage 2 scatter: scatter raw comb rows (fp32) into aggF over all 3 edge lists.
__global__ __launch_bounds__(256) void scatter2(
    const float* __restrict__ comb,
    const int* __restrict__ e0, const int* __restrict__ e1, const int* __restrict__ e2,
    float* __restrict__ aggF) {
    int gid = blockIdx.x * 256 + threadIdx.x;
    int wid = gid >> 6, lane = threadIdx.x & 63;
    int nw = (gridDim.x * 256) >> 6;
    for (int e = wid; e < 3 * NE; e += nw) {
        int t, i;
        if (e < NE) { t = 0; i = e; }
        else if (e < 2 * NE) { t = 1; i = e - NE; }
        else { t = 2; i = e - 2 * NE; }
        const int* ep = (t == 0) ? e0 : ((t == 1) ? e1 : e2);
        int src = ep[i], dst = ep[NE + i];
        float2 v = *(const float2*)(comb + (size_t)src * DD + 2 * lane);
        float* ag = aggF + (size_t)dst * DD + 2 * lane;
        unsafeAtomicAdd(ag, v.x);
        unsafeAtomicAdd(ag + 1, v.y);
    }
}

// GEMM1: comb = relu([mean0|mean1|mean2|meanall|feat] @ Wcat + bias1), K=640.
// Block: 256 thr, 32 nodes. Thread: 4 nodes x 4 feats. Also emits BN partials.
__global__ __launch_bounds__(256) void gemm1(
    const float* __restrict__ feat,
    const float* __restrict__ agg, const float* __restrict__ cnt,
    const float* __restrict__ Wcat, const float* __restrict__ bias1,
    float* __restrict__ comb, float* __restrict__ partials) {
    __shared__ float inS[32][128];
    int tid = threadIdx.x;
    int fq = tid & 31, g = tid >> 5;
    int nb = blockIdx.x * 32;
    float acc[4][4];
#pragma unroll
    for (int j = 0; j < 4; ++j)
#pragma unroll
        for (int m = 0; m < 4; ++m) acc[j][m] = 0.f;

    for (int c = 0; c < 5; ++c) {
        __syncthreads();
#pragma unroll
        for (int r = 0; r < 16; ++r) {
            int idx = tid + r * 256;
            int ln = idx >> 7, k = idx & 127;
            int n = nb + ln;
            float v;
            if (c == 4) {
                v = feat[(size_t)n * DD + k];
            } else if (c == 3) {
                size_t o = (size_t)n * DD + k;
                float s = agg[o] + agg[ND + o] + agg[2 * ND + o];
                float ct = cnt[n] + cnt[NN + n] + cnt[2 * NN + n];
                v = s / fmaxf(ct, 1.0f);
            } else {
                v = agg[(size_t)c * ND + (size_t)n * DD + k] / fmaxf(cnt[c * NN + n], 1.0f);
            }
            inS[ln][k] = v;
        }
        __syncthreads();
        const float* wrow = Wcat + (size_t)c * 128 * 128 + fq * 4;
#pragma unroll 4
        for (int k = 0; k < 128; ++k) {
            float4 w = *(const float4*)(wrow + (size_t)k * 128);
#pragma unroll
            for (int j = 0; j < 4; ++j) {
                float x = inS[g * 4 + j][k];
                acc[j][0] = fmaf(x, w.x, acc[j][0]);
                acc[j][1] = fmaf(x, w.y, acc[j][1]);
                acc[j][2] = fmaf(x, w.z, acc[j][2]);
                acc[j][3] = fmaf(x, w.w, acc[j][3]);
            }
        }
    }
    float bb[4];
    {
        float4 b4 = *(const float4*)(bias1 + fq * 4);
        bb[0] = b4.x; bb[1] = b4.y; bb[2] = b4.z; bb[3] = b4.w;
    }
    float ls[4] = {0.f, 0.f, 0.f, 0.f}, lq[4] = {0.f, 0.f, 0.f, 0.f};
#pragma unroll
    for (int j = 0; j < 4; ++j) {
        int node = nb + g * 4 + j;
        float v[4];
#pragma unroll
        for (int m = 0; m < 4; ++m) {
            float t = fmaxf(acc[j][m] + bb[m], 0.f);
            v[m] = t;
            ls[m] += t;
            lq[m] += t * t;
        }
        *(float4*)(comb + (size_t)node * DD + fq * 4) = make_float4(v[0], v[1], v[2], v[3]);
    }
    __syncthreads();
#pragma unroll
    for (int m = 0; m < 4; ++m) {
        inS[g][fq * 4 + m] = ls[m];
        inS[8 + g][fq * 4 + m] = lq[m];
    }
    __syncthreads();
    if (tid < 128) {
        float s = 0.f, q = 0.f;
#pragma unroll
        for (int g2 = 0; g2 < 8; ++g2) { s += inS[g2][tid]; q += inS[8 + g2][tid]; }
        partials[(size_t)tid * NBLK1 + blockIdx.x] = s;
        partials[(size_t)(128 + tid) * NBLK1 + blockIdx.x] = q;
    }
}

// BN finalize: one block per feature; a = gamma*rsqrt(var+eps), b = beta - mu*a.
__global__ __launch_bounds__(256) void bnfin(
    const float* __restrict__ partials,
    const float* __restrict__ gamma, const float* __restrict__ beta,
    float* __restrict__ bnA, float* __restrict__ bnB) {
    __shared__ float rs[256], rq[256];
    int f = blockIdx.x, tid = threadIdx.x;
    float s = 0.f, q = 0.f;
    for (int r = tid; r < NBLK1; r += 256) {
        s += partials[(size_t)f * NBLK1 + r];
        q += partials[(size_t)(128 + f) * NBLK1 + r];
    }
    rs[tid] = s; rq[tid] = q;
    __syncthreads();
    for (int off = 128; off > 0; off >>= 1) {
        if (tid < off) { rs[tid] += rs[tid + off]; rq[tid] += rq[tid + off]; }
        __syncthreads();
    }
    if (tid == 0) {
        float mu = rs[0] / (float)NN;
        float var = fmaxf(rq[0] / (float)NN - mu * mu, 0.f);
        float a = gamma[f] * rsqrtf(var + 1e-5f);
        bnA[f] = a;
        bnB[f] = beta[f] - mu * a;
    }
}

// GEMM2: out = [meanF_BN | combBN] @ W2cat + bias2, K=256, fp32 out.
__global__ __launch_bounds__(256) void gemm2(
    const float* __restrict__ aggF, const float* __restrict__ cnt,
    const float* __restrict__ comb,
    const float* __restrict__ bnA, const float* __restrict__ bnB,
    const float* __restrict__ W2cat, const float* __restrict__ bias2,
    float* __restrict__ out) {
    __shared__ float inS[32][128];
    int tid = threadIdx.x;
    int fq = tid & 31, g = tid >> 5;
    int nb = blockIdx.x * 32;
    float acc[4][4];
#pragma unroll
    for (int j = 0; j < 4; ++j)
#pragma unroll
        for (int m = 0; m < 4; ++m) acc[j][m] = 0.f;

    for (int c = 0; c < 2; ++c) {
        __syncthreads();
#pragma unroll
        for (int r = 0; r < 16; ++r) {
            int idx = tid + r * 256;
            int ln = idx >> 7, k = idx & 127;
            int n = nb + ln;
            float v;
            if (c == 0) {
                float ct = cnt[n] + cnt[NN + n] + cnt[2 * NN + n];
                float raw = aggF[(size_t)n * DD + k];
                v = (ct > 0.5f) ? (bnA[k] * (raw / ct) + bnB[k]) : 0.f;
            } else {
                v = bnA[k] * comb[(size_t)n * DD + k] + bnB[k];
            }
            inS[ln][k] = v;
        }
        __syncthreads();
        const float* wrow = W2cat + (size_t)c * 128 * 128 + fq * 4;
#pragma unroll 4
        for (int k = 0; k < 128; ++k) {
            float4 w = *(const float4*)(wrow + (size_t)k * 128);
#pragma unroll
            for (int j = 0; j < 4; ++j) {
                float x = inS[g * 4 + j][k];
                acc[j][0] = fmaf(x, w.x, acc[j][0]);
                acc[j][1] = fmaf(x, w.y, acc[j][1]);
                acc[j][2] = fmaf(x, w.z, acc[j][2]);
                acc[j][3] = fmaf(x, w.w, acc[j][3]);
            }
        }
    }
    float bb[4];
    {
        float4 b4 = *(const float4*)(bias2 + fq * 4);
        bb[0] = b4.x; bb[1] = b4.y; bb[2] = b4.z; bb[3] = b4.w;
    }
#pragma unroll
    for (int j = 0; j < 4; ++j) {
        int node = nb + g * 4 + j;
        *(float4*)(out + (size_t)node * DD + fq * 4) =
            make_float4(acc[j][0] + bb[0], acc[j][1] + bb[1],
                        acc[j][2] + bb[2], acc[j][3] + bb[3]);
    }
}

extern "C" void kernel_launch(void* const* d_in, const int* in_sizes, int n_in,
                              void* d_out, int out_size, void* d_ws, size_t ws_size,
                              hipStream_t stream) {
    const float* feat = (const float*)d_in[0];
    const int* e0 = (const int*)d_in[1];
    const int* e1 = (const int*)d_in[2];
    const int* e2 = (const int*)d_in[3];
    const float* Wl0 = (const float*)d_in[4];
    const float* bl0 = (const float*)d_in[5];
    const float* Wr0 = (const float*)d_in[6];
    const float* Wl1 = (const float*)d_in[7];
    const float* bl1 = (const float*)d_in[8];
    const float* Wr1 = (const float*)d_in[9];
    const float* Wl2 = (const float*)d_in[10];
    const float* bl2 = (const float*)d_in[11];
    const float* Wr2 = (const float*)d_in[12];
    const float* Wla = (const float*)d_in[13];
    const float* bla = (const float*)d_in[14];
    const float* Wra = (const float*)d_in[15];
    const float* Wf  = (const float*)d_in[16];
    const float* bfv = (const float*)d_in[17];
    const float* Wrf = (const float*)d_in[18];
    const float* gamma = (const float*)d_in[19];
    const float* beta  = (const float*)d_in[20];
    const float* wt    = (const float*)d_in[21];

    float* ws = (float*)d_ws;
    float* agg   = ws;                       // 3*ND fp32 accumulators
    float* cnt   = ws + 3 * ND;              // 3*NN
    float* comb  = cnt + 3 * NN;             // ND
    float* Wcat  = comb + ND;                // 640*128
    float* bias1 = Wcat + 81920;             // 128
    float* W2cat = bias1 + 128;              // 256*128
    float* bias2 = W2cat + 32768;            // 128
    float* bnA   = bias2 + 128;              // 128
    float* bnB   = bnA + 128;                // 128
    float* partials = bnB + 128;             // 256*NBLK1
    float* aggF  = agg;                      // reused after gemm1 consumes agg

    // zero the atomic accumulators (agg0..2, cnt0..2)
    hipMemsetAsync(d_ws, 0, (size_t)(3 * ND + 3 * NN) * sizeof(float), stream);

    prep_weights<<<449, 256, 0, stream>>>(Wl0, bl0, Wr0, Wl1, bl1, Wr1, Wl2, bl2, Wr2,
                                          Wla, bla, Wra, Wf, bfv, Wrf, wt,
                                          Wcat, bias1, W2cat, bias2);
    scatterA<<<2048, 256, 0, stream>>>(feat, e0, e1, e2, agg, cnt);
    gemm1<<<NBLK1, 256, 0, stream>>>(feat, agg, cnt, Wcat, bias1, comb, partials);
    bnfin<<<128, 256, 0, stream>>>(partials, gamma, beta, bnA, bnB);
    // re-zero agg[0:ND) to serve as aggF for the final aggregation
    hipMemsetAsync(aggF, 0, (size_t)ND * sizeof(float), stream);
    scatter2<<<2048, 256, 0, stream>>>(comb, e0, e1, e2, aggF);
    gemm2<<<NBLK1, 256, 0, stream>>>(aggF, cnt, comb, bnA, bnB, W2cat, bias2,
                                     (float*)d_out);
}

// Round 3
// 858.310 us; speedup vs baseline: 4.0411x; 4.0411x over previous
//
#include <hip/hip_runtime.h>

#define NN 100000
#define NE 300000
#define DD 128
#define NBLK1 3125            // NN/32 (gemm blocks, 32 nodes each)
#define NBLKSEG 49            // ceil(NN/2048) scan blocks per segment

typedef short bf16x8 __attribute__((ext_vector_type(8)));
typedef float f32x4 __attribute__((ext_vector_type(4)));

__device__ __forceinline__ unsigned short f2b(float f) {
    union { float f; unsigned u; } c; c.f = f;
    unsigned u = c.u;
    return (unsigned short)((u + 0x7fffu + ((u >> 16) & 1u)) >> 16);
}
__device__ __forceinline__ float b2f(unsigned s) {
    union { float f; unsigned u; } c; c.u = s << 16; return c.f;
}

// ---------- weight prep: bf16 WcatB[128][640], W2catB[128][256], fp32 biases ----------
__global__ __launch_bounds__(256) void prep_weights(
    const float* __restrict__ Wl0, const float* __restrict__ bl0, const float* __restrict__ Wr0,
    const float* __restrict__ Wl1, const float* __restrict__ bl1, const float* __restrict__ Wr1,
    const float* __restrict__ Wl2, const float* __restrict__ bl2, const float* __restrict__ Wr2,
    const float* __restrict__ Wla, const float* __restrict__ bla, const float* __restrict__ Wra,
    const float* __restrict__ Wf,  const float* __restrict__ bfv, const float* __restrict__ Wrf,
    const float* __restrict__ wt,
    unsigned short* __restrict__ WcatB, float* __restrict__ bias1,
    unsigned short* __restrict__ W2catB, float* __restrict__ bias2) {
    int idx = blockIdx.x * 256 + threadIdx.x;
    float w0 = wt[0], w1 = wt[1], w2 = wt[2];
    if (idx < 81920) {
        int f = idx / 640, k = idx % 640;   // row-major [f][kcat]
        float v;
        if (k < 128)      v = w0 * Wl0[f * 128 + k];
        else if (k < 256) v = w1 * Wl1[f * 128 + (k - 128)];
        else if (k < 384) v = w2 * Wl2[f * 128 + (k - 256)];
        else if (k < 512) v = Wla[f * 128 + (k - 384)];
        else {
            int kk = k - 512;
            v = w0 * Wr0[f * 128 + kk] + w1 * Wr1[f * 128 + kk] +
                w2 * Wr2[f * 128 + kk] + Wra[f * 128 + kk];
        }
        WcatB[idx] = f2b(v);
    } else if (idx < 81920 + 32768) {
        int j = idx - 81920;
        int f = j >> 8, k = j & 255;        // [f][k], K=256
        W2catB[j] = f2b((k < 128) ? Wf[f * 128 + k] : Wrf[f * 128 + (k - 128)]);
    } else if (idx < 81920 + 32768 + 128) {
        int f = idx - (81920 + 32768);
        bias1[f] = w0 * bl0[f] + w1 * bl1[f] + w2 * bl2[f] + bla[f];
        bias2[f] = bfv[f];
    }
}

// ---------- CSR build ----------
__global__ __launch_bounds__(256) void count_deg(
    const int* __restrict__ e0, const int* __restrict__ e1, const int* __restrict__ e2,
    int* __restrict__ deg) {
    int gid = blockIdx.x * 256 + threadIdx.x;
    if (gid >= 3 * NE) return;
    int t = (gid < NE) ? 0 : ((gid < 2 * NE) ? 1 : 2);
    int i = gid - t * NE;
    const int* ep = (t == 0) ? e0 : ((t == 1) ? e1 : e2);
    int dst = ep[NE + i];
    atomicAdd(&deg[t * NN + dst], 1);
}

__global__ __launch_bounds__(256) void scan_local(
    const int* __restrict__ deg, int* __restrict__ rowstart, int* __restrict__ bsum) {
    __shared__ int sc[256];
    int b = blockIdx.x, tid = threadIdx.x;
    int seg = b / NBLKSEG, blk = b % NBLKSEG;
    int g0 = seg * NN;
    int base = blk * 2048 + tid * 8;
    int vals[8]; int tsum = 0;
#pragma unroll
    for (int j = 0; j < 8; ++j) {
        int l = base + j;
        int d = (l < NN) ? deg[g0 + l] : 0;
        vals[j] = tsum; tsum += d;
    }
    sc[tid] = tsum;
    __syncthreads();
    for (int off = 1; off < 256; off <<= 1) {
        int v = (tid >= off) ? sc[tid - off] : 0;
        __syncthreads();
        sc[tid] += v;
        __syncthreads();
    }
    int excl = sc[tid] - tsum;
#pragma unroll
    for (int j = 0; j < 8; ++j) {
        int l = base + j;
        if (l < NN) rowstart[g0 + l] = excl + vals[j];
    }
    if (tid == 255) bsum[b] = sc[255];
}

__global__ void scan_bsum(int* __restrict__ bsum) {
    int tid = threadIdx.x;
    if (tid < 3) {
        int run = 0;
        for (int b = 0; b < NBLKSEG; ++b) {
            int idx = tid * NBLKSEG + b;
            int t = bsum[idx]; bsum[idx] = run; run += t;
        }
    }
}

__global__ __launch_bounds__(256) void scan_fix(
    int* __restrict__ rowstart, int* __restrict__ fillpos, const int* __restrict__ bsum) {
    int b = blockIdx.x, tid = threadIdx.x;
    int seg = b / NBLKSEG, blk = b % NBLKSEG;
    int g0 = seg * NN;
    int base = blk * 2048 + tid * 8;
    int off = bsum[b];
#pragma unroll
    for (int j = 0; j < 8; ++j) {
        int l = base + j;
        if (l < NN) {
            int r = rowstart[g0 + l] + off;
            rowstart[g0 + l] = r;
            fillpos[g0 + l] = r;
        }
    }
}

__global__ __launch_bounds__(256) void fill_csr(
    const int* __restrict__ e0, const int* __restrict__ e1, const int* __restrict__ e2,
    int* __restrict__ fillpos, int* __restrict__ csr) {
    int gid = blockIdx.x * 256 + threadIdx.x;
    if (gid >= 3 * NE) return;
    int t = (gid < NE) ? 0 : ((gid < 2 * NE) ? 1 : 2);
    int i = gid - t * NE;
    const int* ep = (t == 0) ? e0 : ((t == 1) ? e1 : e2);
    int src = ep[i], dst = ep[NE + i];
    int p = atomicAdd(&fillpos[t * NN + dst], 1);
    csr[t * NE + p] = src;
}

// ---------- gemm1: gather means + MFMA, K=640, emits comb(bf16) + BN partials ----------
__global__ __launch_bounds__(256) void gemm1_fused(
    const float* __restrict__ feat,
    const int* __restrict__ deg, const int* __restrict__ rowstart, const int* __restrict__ csr,
    const unsigned short* __restrict__ WcatB, const float* __restrict__ bias1,
    unsigned short* __restrict__ comb, float* __restrict__ partials) {
    __shared__ unsigned short As[32][648];   // 32 nodes x 640 k (+8 pad)
    __shared__ float bnS[128], bnQ[128];
    int tid = threadIdx.x;
    int wid = tid >> 6, lane = tid & 63;
    int nb = blockIdx.x * 32;
    if (tid < 128) { bnS[tid] = 0.f; bnQ[tid] = 0.f; }

    // gather phase: wave handles 8 nodes
    for (int ln = wid * 8; ln < wid * 8 + 8; ++ln) {
        int n = nb + ln;
        float aAx = 0.f, aAy = 0.f; int dall = 0;
#pragma unroll
        for (int t = 0; t < 3; ++t) {
            int d = deg[t * NN + n];
            int rs = rowstart[t * NN + n];
            float ax = 0.f, ay = 0.f;
            for (int j = 0; j < d; ++j) {
                int src = csr[t * NE + rs + j];
                float2 v = *(const float2*)(feat + (size_t)src * DD + lane * 2);
                ax += v.x; ay += v.y;
            }
            aAx += ax; aAy += ay; dall += d;
            float inv = 1.0f / fmaxf((float)d, 1.0f);
            As[ln][t * 128 + lane * 2]     = f2b(ax * inv);
            As[ln][t * 128 + lane * 2 + 1] = f2b(ay * inv);
        }
        float invA = 1.0f / fmaxf((float)dall, 1.0f);
        As[ln][384 + lane * 2]     = f2b(aAx * invA);
        As[ln][384 + lane * 2 + 1] = f2b(aAy * invA);
        float2 sv = *(const float2*)(feat + (size_t)n * DD + lane * 2);
        As[ln][512 + lane * 2]     = f2b(sv.x);
        As[ln][512 + lane * 2 + 1] = f2b(sv.y);
    }
    __syncthreads();

    // MFMA phase: wave (wid>>1) picks node half, (wid&1) picks feature half
    int quad = lane >> 4, m16 = lane & 15;
    int mrow = (wid >> 1) * 16;
    int fbase = (wid & 1) * 64;
    f32x4 acc[4];
#pragma unroll
    for (int ft = 0; ft < 4; ++ft) acc[ft] = (f32x4){0.f, 0.f, 0.f, 0.f};

    for (int kk = 0; kk < 20; ++kk) {
        int k0 = kk * 32 + quad * 8;
        bf16x8 av = *(const bf16x8*)&As[mrow + m16][k0];
#pragma unroll
        for (int ft = 0; ft < 4; ++ft) {
            int f = fbase + ft * 16 + m16;
            bf16x8 bv = *(const bf16x8*)&WcatB[(size_t)f * 640 + k0];
            acc[ft] = __builtin_amdgcn_mfma_f32_16x16x32_bf16(av, bv, acc[ft], 0, 0, 0);
        }
    }

    // epilogue: bias + relu, BN partial sums, bf16 comb store
#pragma unroll
    for (int ft = 0; ft < 4; ++ft) {
        int f = fbase + ft * 16 + m16;
        float bb = bias1[f];
        float s = 0.f, q = 0.f;
#pragma unroll
        for (int r = 0; r < 4; ++r) {
            int m = mrow + quad * 4 + r;
            int node = nb + m;
            float v = fmaxf(acc[ft][r] + bb, 0.f);
            s += v; q += v * v;
            comb[(size_t)node * DD + f] = f2b(v);
        }
        atomicAdd(&bnS[f], s);
        atomicAdd(&bnQ[f], q);
    }
    __syncthreads();
    if (tid < 128) {
        partials[(size_t)tid * NBLK1 + blockIdx.x] = bnS[tid];
        partials[(size_t)(128 + tid) * NBLK1 + blockIdx.x] = bnQ[tid];
    }
}

// ---------- BN finalize ----------
__global__ __launch_bounds__(256) void bnfin(
    const float* __restrict__ partials,
    const float* __restrict__ gamma, const float* __restrict__ beta,
    float* __restrict__ bnA, float* __restrict__ bnB) {
    __shared__ float rs[256], rq[256];
    int f = blockIdx.x, tid = threadIdx.x;
    float s = 0.f, q = 0.f;
    for (int r = tid; r < NBLK1; r += 256) {
        s += partials[(size_t)f * NBLK1 + r];
        q += partials[(size_t)(128 + f) * NBLK1 + r];
    }
    rs[tid] = s; rq[tid] = q;
    __syncthreads();
    for (int off = 128; off > 0; off >>= 1) {
        if (tid < off) { rs[tid] += rs[tid + off]; rq[tid] += rq[tid + off]; }
        __syncthreads();
    }
    if (tid == 0) {
        float mu = rs[0] / (float)NN;
        float var = fmaxf(rq[0] / (float)NN - mu * mu, 0.f);
        float a = gamma[f] * rsqrtf(var + 1e-5f);
        bnA[f] = a;
        bnB[f] = beta[f] - mu * a;
    }
}

// ---------- gemm2: gather comb means + MFMA, K=256, fp32 out ----------
__global__ __launch_bounds__(256) void gemm2_fused(
    const unsigned short* __restrict__ comb,
    const int* __restrict__ deg, const int* __restrict__ rowstart, const int* __restrict__ csr,
    const float* __restrict__ bnA, const float* __restrict__ bnB,
    const unsigned short* __restrict__ W2catB, const float* __restrict__ bias2,
    float* __restrict__ out) {
    __shared__ unsigned short As[32][264];   // 32 nodes x 256 k (+8 pad)
    int tid = threadIdx.x;
    int wid = tid >> 6, lane = tid & 63;
    int nb = blockIdx.x * 32;
    const unsigned* combU = (const unsigned*)comb;

    float2 a2 = *(const float2*)&bnA[lane * 2];
    float2 b2 = *(const float2*)&bnB[lane * 2];

    for (int ln = wid * 8; ln < wid * 8 + 8; ++ln) {
        int n = nb + ln;
        float ax = 0.f, ay = 0.f; int dall = 0;
#pragma unroll
        for (int t = 0; t < 3; ++t) {
            int d = deg[t * NN + n];
            int rs = rowstart[t * NN + n];
            for (int j = 0; j < d; ++j) {
                int src = csr[t * NE + rs + j];
                unsigned u = combU[(size_t)src * 64 + lane];
                ax += b2f(u & 0xffffu); ay += b2f(u >> 16);
            }
            dall += d;
        }
        float vx = 0.f, vy = 0.f;
        if (dall > 0) {
            float inv = 1.0f / (float)dall;
            vx = a2.x * (ax * inv) + b2.x;
            vy = a2.y * (ay * inv) + b2.y;
        }
        As[ln][lane * 2]     = f2b(vx);
        As[ln][lane * 2 + 1] = f2b(vy);
        unsigned us = combU[(size_t)n * 64 + lane];
        As[ln][128 + lane * 2]     = f2b(a2.x * b2f(us & 0xffffu) + b2.x);
        As[ln][128 + lane * 2 + 1] = f2b(a2.y * b2f(us >> 16) + b2.y);
    }
    __syncthreads();

    int quad = lane >> 4, m16 = lane & 15;
    int mrow = (wid >> 1) * 16;
    int fbase = (wid & 1) * 64;
    f32x4 acc[4];
#pragma unroll
    for (int ft = 0; ft < 4; ++ft) acc[ft] = (f32x4){0.f, 0.f, 0.f, 0.f};

    for (int kk = 0; kk < 8; ++kk) {
        int k0 = kk * 32 + quad * 8;
        bf16x8 av = *(const bf16x8*)&As[mrow + m16][k0];
#pragma unroll
        for (int ft = 0; ft < 4; ++ft) {
            int f = fbase + ft * 16 + m16;
            bf16x8 bv = *(const bf16x8*)&W2catB[(size_t)f * 256 + k0];
            acc[ft] = __builtin_amdgcn_mfma_f32_16x16x32_bf16(av, bv, acc[ft], 0, 0, 0);
        }
    }

#pragma unroll
    for (int ft = 0; ft < 4; ++ft) {
        int f = fbase + ft * 16 + m16;
        float bb = bias2[f];
#pragma unroll
        for (int r = 0; r < 4; ++r) {
            int m = mrow + quad * 4 + r;
            int node = nb + m;
            out[(size_t)node * DD + f] = acc[ft][r] + bb;
        }
    }
}

extern "C" void kernel_launch(void* const* d_in, const int* in_sizes, int n_in,
                              void* d_out, int out_size, void* d_ws, size_t ws_size,
                              hipStream_t stream) {
    const float* feat = (const float*)d_in[0];
    const int* e0 = (const int*)d_in[1];
    const int* e1 = (const int*)d_in[2];
    const int* e2 = (const int*)d_in[3];
    const float* Wl0 = (const float*)d_in[4];
    const float* bl0 = (const float*)d_in[5];
    const float* Wr0 = (const float*)d_in[6];
    const float* Wl1 = (const float*)d_in[7];
    const float* bl1 = (const float*)d_in[8];
    const float* Wr1 = (const float*)d_in[9];
    const float* Wl2 = (const float*)d_in[10];
    const float* bl2 = (const float*)d_in[11];
    const float* Wr2 = (const float*)d_in[12];
    const float* Wla = (const float*)d_in[13];
    const float* bla = (const float*)d_in[14];
    const float* Wra = (const float*)d_in[15];
    const float* Wf  = (const float*)d_in[16];
    const float* bfv = (const float*)d_in[17];
    const float* Wrf = (const float*)d_in[18];
    const float* gamma = (const float*)d_in[19];
    const float* beta  = (const float*)d_in[20];
    const float* wt    = (const float*)d_in[21];

    int* deg      = (int*)d_ws;              // 3*NN
    int* rowstart = deg + 3 * NN;            // 3*NN
    int* fillpos  = rowstart + 3 * NN;       // 3*NN
    int* csr      = fillpos + 3 * NN;        // 3*NE
    int* bsum     = csr + 3 * NE;            // 147 (pad 160)
    float* partials = (float*)(bsum + 160);  // 256*NBLK1
    float* bias1  = partials + 256 * NBLK1;  // 128
    float* bias2  = bias1 + 128;             // 128
    float* bnA    = bias2 + 128;             // 128
    float* bnB    = bnA + 128;               // 128
    unsigned short* WcatB  = (unsigned short*)(bnB + 128);   // 128*640
    unsigned short* W2catB = WcatB + 81920;                  // 128*256
    unsigned short* comb   = W2catB + 32768;                 // NN*128

    hipMemsetAsync(deg, 0, (size_t)3 * NN * sizeof(int), stream);

    prep_weights<<<449, 256, 0, stream>>>(Wl0, bl0, Wr0, Wl1, bl1, Wr1, Wl2, bl2, Wr2,
                                          Wla, bla, Wra, Wf, bfv, Wrf, wt,
                                          WcatB, bias1, W2catB, bias2);
    count_deg<<<3516, 256, 0, stream>>>(e0, e1, e2, deg);
    scan_local<<<147, 256, 0, stream>>>(deg, rowstart, bsum);
    scan_bsum<<<1, 64, 0, stream>>>(bsum);
    scan_fix<<<147, 256, 0, stream>>>(rowstart, fillpos, bsum);
    fill_csr<<<3516, 256, 0, stream>>>(e0, e1, e2, fillpos, csr);

    gemm1_fused<<<NBLK1, 256, 0, stream>>>(feat, deg, rowstart, csr, WcatB, bias1,
                                           comb, partials);
    bnfin<<<128, 256, 0, stream>>>(partials, gamma, beta, bnA, bnB);
    gemm2_fused<<<NBLK1, 256, 0, stream>>>(comb, deg, rowstart, csr, bnA, bnB,
                                           W2catB, bias2, (float*)d_out);
}

// Round 5
// 659.113 us; speedup vs baseline: 5.2624x; 1.3022x over previous
//
#include <hip/hip_runtime.h>

#define NN 100000
#define NE 300000
#define DD 128
#define NBLK1 3125            // NN/32 (gemm blocks, 32 nodes each)
#define NBLKSEG 49            // ceil(NN/2048) scan blocks per segment
#define IDXCAP 768            // per-etype per-block LDS index cache

typedef short bf16x8 __attribute__((ext_vector_type(8)));
typedef float f32x4 __attribute__((ext_vector_type(4)));

__device__ __forceinline__ unsigned short f2b(float f) {
    union { float f; unsigned u; } c; c.f = f;
    unsigned u = c.u;
    return (unsigned short)((u + 0x7fffu + ((u >> 16) & 1u)) >> 16);
}
__device__ __forceinline__ float b2lo(unsigned u) {   // low bf16 -> f32
    union { float f; unsigned u; } c; c.u = u << 16; return c.f;
}
__device__ __forceinline__ float b2hi(unsigned u) {   // high bf16 -> f32
    union { float f; unsigned u; } c; c.u = u & 0xffff0000u; return c.f;
}
__device__ __forceinline__ unsigned pack2(float lo, float hi) {
    return (unsigned)f2b(lo) | ((unsigned)f2b(hi) << 16);
}

// ---------- feat -> bf16 ----------
__global__ __launch_bounds__(256) void feat_to_bf16(
    const float* __restrict__ feat, unsigned short* __restrict__ fb) {
    int gid = blockIdx.x * 256 + threadIdx.x;   // one uint4 (8 elems) per thread
    if (gid >= NN * 16) return;
    const float4* f4 = (const float4*)feat;
    float4 a = f4[gid * 2], b = f4[gid * 2 + 1];
    uint4 o;
    o.x = pack2(a.x, a.y); o.y = pack2(a.z, a.w);
    o.z = pack2(b.x, b.y); o.w = pack2(b.z, b.w);
    ((uint4*)fb)[gid] = o;
}

// ---------- weight prep: bf16 WcatB[128][640], W2catB[128][256], fp32 biases ----------
__global__ __launch_bounds__(256) void prep_weights(
    const float* __restrict__ Wl0, const float* __restrict__ bl0, const float* __restrict__ Wr0,
    const float* __restrict__ Wl1, const float* __restrict__ bl1, const float* __restrict__ Wr1,
    const float* __restrict__ Wl2, const float* __restrict__ bl2, const float* __restrict__ Wr2,
    const float* __restrict__ Wla, const float* __restrict__ bla, const float* __restrict__ Wra,
    const float* __restrict__ Wf,  const float* __restrict__ bfv, const float* __restrict__ Wrf,
    const float* __restrict__ wt,
    unsigned short* __restrict__ WcatB, float* __restrict__ bias1,
    unsigned short* __restrict__ W2catB, float* __restrict__ bias2) {
    int idx = blockIdx.x * 256 + threadIdx.x;
    float w0 = wt[0], w1 = wt[1], w2 = wt[2];
    if (idx < 81920) {
        int f = idx / 640, k = idx % 640;   // row-major [f][kcat]
        float v;
        if (k < 128)      v = w0 * Wl0[f * 128 + k];
        else if (k < 256) v = w1 * Wl1[f * 128 + (k - 128)];
        else if (k < 384) v = w2 * Wl2[f * 128 + (k - 256)];
        else if (k < 512) v = Wla[f * 128 + (k - 384)];
        else {
            int kk = k - 512;
            v = w0 * Wr0[f * 128 + kk] + w1 * Wr1[f * 128 + kk] +
                w2 * Wr2[f * 128 + kk] + Wra[f * 128 + kk];
        }
        WcatB[idx] = f2b(v);
    } else if (idx < 81920 + 32768) {
        int j = idx - 81920;
        int f = j >> 8, k = j & 255;        // [f][k], K=256
        W2catB[j] = f2b((k < 128) ? Wf[f * 128 + k] : Wrf[f * 128 + (k - 128)]);
    } else if (idx < 81920 + 32768 + 128) {
        int f = idx - (81920 + 32768);
        bias1[f] = w0 * bl0[f] + w1 * bl1[f] + w2 * bl2[f] + bla[f];
        bias2[f] = bfv[f];
    }
}

// ---------- CSR build ----------
__global__ __launch_bounds__(256) void count_deg(
    const int* __restrict__ e0, const int* __restrict__ e1, const int* __restrict__ e2,
    int* __restrict__ deg) {
    int gid = blockIdx.x * 256 + threadIdx.x;
    if (gid >= 3 * NE) return;
    int t = (gid < NE) ? 0 : ((gid < 2 * NE) ? 1 : 2);
    int i = gid - t * NE;
    const int* ep = (t == 0) ? e0 : ((t == 1) ? e1 : e2);
    int dst = ep[NE + i];
    atomicAdd(&deg[t * NN + dst], 1);
}

__global__ __launch_bounds__(256) void scan_local(
    const int* __restrict__ deg, int* __restrict__ rowstart, int* __restrict__ bsum) {
    __shared__ int sc[256];
    int b = blockIdx.x, tid = threadIdx.x;
    int seg = b / NBLKSEG, blk = b % NBLKSEG;
    int g0 = seg * NN;
    int base = blk * 2048 + tid * 8;
    int vals[8]; int tsum = 0;
#pragma unroll
    for (int j = 0; j < 8; ++j) {
        int l = base + j;
        int d = (l < NN) ? deg[g0 + l] : 0;
        vals[j] = tsum; tsum += d;
    }
    sc[tid] = tsum;
    __syncthreads();
    for (int off = 1; off < 256; off <<= 1) {
        int v = (tid >= off) ? sc[tid - off] : 0;
        __syncthreads();
        sc[tid] += v;
        __syncthreads();
    }
    int excl = sc[tid] - tsum;
#pragma unroll
    for (int j = 0; j < 8; ++j) {
        int l = base + j;
        if (l < NN) rowstart[g0 + l] = excl + vals[j];
    }
    if (tid == 255) bsum[b] = sc[255];
}

__global__ void scan_bsum(int* __restrict__ bsum) {
    int tid = threadIdx.x;
    if (tid < 3) {
        int run = 0;
        for (int b = 0; b < NBLKSEG; ++b) {
            int idx = tid * NBLKSEG + b;
            int t = bsum[idx]; bsum[idx] = run; run += t;
        }
    }
}

__global__ __launch_bounds__(256) void scan_fix(
    int* __restrict__ rowstart, int* __restrict__ fillpos, const int* __restrict__ bsum) {
    int b = blockIdx.x, tid = threadIdx.x;
    int seg = b / NBLKSEG, blk = b % NBLKSEG;
    int g0 = seg * NN;
    int base = blk * 2048 + tid * 8;
    int off = bsum[b];
#pragma unroll
    for (int j = 0; j < 8; ++j) {
        int l = base + j;
        if (l < NN) {
            int r = rowstart[g0 + l] + off;
            rowstart[g0 + l] = r;
            fillpos[g0 + l] = r;
        }
    }
}

__global__ __launch_bounds__(256) void fill_csr(
    const int* __restrict__ e0, const int* __restrict__ e1, const int* __restrict__ e2,
    int* __restrict__ fillpos, int* __restrict__ csr) {
    int gid = blockIdx.x * 256 + threadIdx.x;
    if (gid >= 3 * NE) return;
    int t = (gid < NE) ? 0 : ((gid < 2 * NE) ? 1 : 2);
    int i = gid - t * NE;
    const int* ep = (t == 0) ? e0 : ((t == 1) ? e1 : e2);
    int src = ep[i], dst = ep[NE + i];
    int p = atomicAdd(&fillpos[t * NN + dst], 1);
    csr[t * NE + p] = src;
}

// ---------- gemm1: gather means (bf16 feat) + MFMA, K=640 ----------
__global__ __launch_bounds__(256) void gemm1_fused(
    const unsigned short* __restrict__ featB,
    const int* __restrict__ deg, const int* __restrict__ rowstart, const int* __restrict__ csr,
    const unsigned short* __restrict__ WcatB, const float* __restrict__ bias1,
    unsigned short* __restrict__ comb, float* __restrict__ partials) {
    __shared__ unsigned short As[32][648];   // 32 nodes x 640 k (+8 pad)
    __shared__ int idxS[3][IDXCAP];
    __shared__ int startS[3], cntS[3];
    __shared__ float bnS[128], bnQ[128];
    int tid = threadIdx.x;
    int wid = tid >> 6, lane = tid & 63;
    int slot = lane >> 4, fq = lane & 15;
    int nb = blockIdx.x * 32;
    if (tid < 128) { bnS[tid] = 0.f; bnQ[tid] = 0.f; }
    if (tid < 3) {
        int s = rowstart[tid * NN + nb];
        int e = (nb + 32 < NN) ? rowstart[tid * NN + nb + 32] : NE;
        startS[tid] = s; cntS[tid] = e - s;
    }
    __syncthreads();
#pragma unroll
    for (int t = 0; t < 3; ++t) {
        int c = min(cntS[t], IDXCAP), s0 = startS[t];
        for (int p = tid; p < c; p += 256) idxS[t][p] = csr[t * NE + s0 + p];
    }
    // self rows: straight bf16 copy (32 rows x 16 chunks of 8 shorts)
    for (int it = tid; it < 512; it += 256) {
        int row = it >> 4, grp = it & 15;
        uint4 v = *(const uint4*)(featB + (size_t)(nb + row) * DD + grp * 8);
        *(uint4*)&As[row][512 + grp * 8] = v;
    }
    __syncthreads();

    // gather: wave handles 8 nodes; 4 edge-slots x 16 lanes x 16B
    for (int ln = wid * 8; ln < wid * 8 + 8; ++ln) {
        int n = nb + ln;
        float aA[8] = {0.f, 0.f, 0.f, 0.f, 0.f, 0.f, 0.f, 0.f};
        int dall = 0;
#pragma unroll
        for (int t = 0; t < 3; ++t) {
            int d = deg[t * NN + n];
            int r0 = rowstart[t * NN + n] - startS[t];
            float ac[8] = {0.f, 0.f, 0.f, 0.f, 0.f, 0.f, 0.f, 0.f};
            for (int j = slot; j < d; j += 4) {
                int p = r0 + j;
                int src = (p < IDXCAP) ? idxS[t][p] : csr[(size_t)t * NE + startS[t] + p];
                uint4 v = *(const uint4*)(featB + (size_t)src * DD + fq * 8);
                ac[0] += b2lo(v.x); ac[1] += b2hi(v.x);
                ac[2] += b2lo(v.y); ac[3] += b2hi(v.y);
                ac[4] += b2lo(v.z); ac[5] += b2hi(v.z);
                ac[6] += b2lo(v.w); ac[7] += b2hi(v.w);
            }
#pragma unroll
            for (int i = 0; i < 8; ++i) {
                ac[i] += __shfl_xor(ac[i], 16);
                ac[i] += __shfl_xor(ac[i], 32);
                aA[i] += ac[i];
            }
            dall += d;
            if (slot == 0) {
                float inv = 1.0f / fmaxf((float)d, 1.0f);
                uint4 o;
                o.x = pack2(ac[0] * inv, ac[1] * inv);
                o.y = pack2(ac[2] * inv, ac[3] * inv);
                o.z = pack2(ac[4] * inv, ac[5] * inv);
                o.w = pack2(ac[6] * inv, ac[7] * inv);
                *(uint4*)&As[ln][t * 128 + fq * 8] = o;
            }
        }
        if (slot == 0) {
            float inv = 1.0f / fmaxf((float)dall, 1.0f);
            uint4 o;
            o.x = pack2(aA[0] * inv, aA[1] * inv);
            o.y = pack2(aA[2] * inv, aA[3] * inv);
            o.z = pack2(aA[4] * inv, aA[5] * inv);
            o.w = pack2(aA[6] * inv, aA[7] * inv);
            *(uint4*)&As[ln][384 + fq * 8] = o;
        }
    }
    __syncthreads();

    // MFMA phase
    int quad = lane >> 4, m16 = lane & 15;
    int mrow = (wid >> 1) * 16;
    int fbase = (wid & 1) * 64;
    f32x4 acc[4];
#pragma unroll
    for (int ft = 0; ft < 4; ++ft) acc[ft] = (f32x4){0.f, 0.f, 0.f, 0.f};

    for (int kk = 0; kk < 20; ++kk) {
        int k0 = kk * 32 + quad * 8;
        bf16x8 av = *(const bf16x8*)&As[mrow + m16][k0];
#pragma unroll
        for (int ft = 0; ft < 4; ++ft) {
            int f = fbase + ft * 16 + m16;
            bf16x8 bv = *(const bf16x8*)&WcatB[(size_t)f * 640 + k0];
            acc[ft] = __builtin_amdgcn_mfma_f32_16x16x32_bf16(av, bv, acc[ft], 0, 0, 0);
        }
    }

#pragma unroll
    for (int ft = 0; ft < 4; ++ft) {
        int f = fbase + ft * 16 + m16;
        float bb = bias1[f];
        float s = 0.f, q = 0.f;
#pragma unroll
        for (int r = 0; r < 4; ++r) {
            int m = mrow + quad * 4 + r;
            int node = nb + m;
            float v = fmaxf(acc[ft][r] + bb, 0.f);
            s += v; q += v * v;
            comb[(size_t)node * DD + f] = f2b(v);
        }
        atomicAdd(&bnS[f], s);
        atomicAdd(&bnQ[f], q);
    }
    __syncthreads();
    if (tid < 128) {
        partials[(size_t)tid * NBLK1 + blockIdx.x] = bnS[tid];
        partials[(size_t)(128 + tid) * NBLK1 + blockIdx.x] = bnQ[tid];
    }
}

// ---------- BN finalize ----------
__global__ __launch_bounds__(256) void bnfin(
    const float* __restrict__ partials,
    const float* __restrict__ gamma, const float* __restrict__ beta,
    float* __restrict__ bnA, float* __restrict__ bnB) {
    __shared__ float rs[256], rq[256];
    int f = blockIdx.x, tid = threadIdx.x;
    float s = 0.f, q = 0.f;
    for (int r = tid; r < NBLK1; r += 256) {
        s += partials[(size_t)f * NBLK1 + r];
        q += partials[(size_t)(128 + f) * NBLK1 + r];
    }
    rs[tid] = s; rq[tid] = q;
    __syncthreads();
    for (int off = 128; off > 0; off >>= 1) {
        if (tid < off) { rs[tid] += rs[tid + off]; rq[tid] += rq[tid + off]; }
        __syncthreads();
    }
    if (tid == 0) {
        float mu = rs[0] / (float)NN;
        float var = fmaxf(rq[0] / (float)NN - mu * mu, 0.f);
        float a = gamma[f] * rsqrtf(var + 1e-5f);
        bnA[f] = a;
        bnB[f] = beta[f] - mu * a;
    }
}

// ---------- gemm2: gather comb means + MFMA, K=256, fp32 out ----------
__global__ __launch_bounds__(256) void gemm2_fused(
    const unsigned short* __restrict__ comb,
    const int* __restrict__ deg, const int* __restrict__ rowstart, const int* __restrict__ csr,
    const float* __restrict__ bnA, const float* __restrict__ bnB,
    const unsigned short* __restrict__ W2catB, const float* __restrict__ bias2,
    float* __restrict__ out) {
    __shared__ unsigned short As[32][264];   // 32 nodes x 256 k (+8 pad)
    __shared__ int idxS[3][IDXCAP];
    __shared__ int startS[3], cntS[3];
    int tid = threadIdx.x;
    int wid = tid >> 6, lane = tid & 63;
    int slot = lane >> 4, fq = lane & 15;
    int nb = blockIdx.x * 32;
    if (tid < 3) {
        int s = rowstart[tid * NN + nb];
        int e = (nb + 32 < NN) ? rowstart[tid * NN + nb + 32] : NE;
        startS[tid] = s; cntS[tid] = e - s;
    }
    __syncthreads();
#pragma unroll
    for (int t = 0; t < 3; ++t) {
        int c = min(cntS[t], IDXCAP), s0 = startS[t];
        for (int p = tid; p < c; p += 256) idxS[t][p] = csr[t * NE + s0 + p];
    }
    // self rows with BN affine (32 rows x 16 chunks of 8 shorts)
    for (int it = tid; it < 512; it += 256) {
        int row = it >> 4, grp = it & 15;
        uint4 v = *(const uint4*)(comb + (size_t)(nb + row) * DD + grp * 8);
        float4 a0 = *(const float4*)&bnA[grp * 8], a1 = *(const float4*)&bnA[grp * 8 + 4];
        float4 b0 = *(const float4*)&bnB[grp * 8], b1 = *(const float4*)&bnB[grp * 8 + 4];
        uint4 o;
        o.x = pack2(a0.x * b2lo(v.x) + b0.x, a0.y * b2hi(v.x) + b0.y);
        o.y = pack2(a0.z * b2lo(v.y) + b0.z, a0.w * b2hi(v.y) + b0.w);
        o.z = pack2(a1.x * b2lo(v.z) + b1.x, a1.y * b2hi(v.z) + b1.y);
        o.w = pack2(a1.z * b2lo(v.w) + b1.z, a1.w * b2hi(v.w) + b1.w);
        *(uint4*)&As[row][128 + grp * 8] = o;
    }
    __syncthreads();

    for (int ln = wid * 8; ln < wid * 8 + 8; ++ln) {
        int n = nb + ln;
        float ac[8] = {0.f, 0.f, 0.f, 0.f, 0.f, 0.f, 0.f, 0.f};
        int dall = 0;
#pragma unroll
        for (int t = 0; t < 3; ++t) {
            int d = deg[t * NN + n];
            int r0 = rowstart[t * NN + n] - startS[t];
            for (int j = slot; j < d; j += 4) {
                int p = r0 + j;
                int src = (p < IDXCAP) ? idxS[t][p] : csr[(size_t)t * NE + startS[t] + p];
                uint4 v = *(const uint4*)(comb + (size_t)src * DD + fq * 8);
                ac[0] += b2lo(v.x); ac[1] += b2hi(v.x);
                ac[2] += b2lo(v.y); ac[3] += b2hi(v.y);
                ac[4] += b2lo(v.z); ac[5] += b2hi(v.z);
                ac[6] += b2lo(v.w); ac[7] += b2hi(v.w);
            }
            dall += d;
        }
#pragma unroll
        for (int i = 0; i < 8; ++i) {
            ac[i] += __shfl_xor(ac[i], 16);
            ac[i] += __shfl_xor(ac[i], 32);
        }
        if (slot == 0) {
            float inv = (dall > 0) ? 1.0f / (float)dall : 0.f;
            float4 a0 = *(const float4*)&bnA[fq * 8], a1 = *(const float4*)&bnA[fq * 8 + 4];
            float4 b0 = *(const float4*)&bnB[fq * 8], b1 = *(const float4*)&bnB[fq * 8 + 4];
            float v0 = 0.f, v1 = 0.f, v2 = 0.f, v3 = 0.f, v4 = 0.f, v5 = 0.f, v6 = 0.f, v7 = 0.f;
            if (dall > 0) {
                v0 = a0.x * (ac[0] * inv) + b0.x; v1 = a0.y * (ac[1] * inv) + b0.y;
                v2 = a0.z * (ac[2] * inv) + b0.z; v3 = a0.w * (ac[3] * inv) + b0.w;
                v4 = a1.x * (ac[4] * inv) + b1.x; v5 = a1.y * (ac[5] * inv) + b1.y;
                v6 = a1.z * (ac[6] * inv) + b1.z; v7 = a1.w * (ac[7] * inv) + b1.w;
            }
            uint4 o;
            o.x = pack2(v0, v1); o.y = pack2(v2, v3);
            o.z = pack2(v4, v5); o.w = pack2(v6, v7);
            *(uint4*)&As[ln][fq * 8] = o;
        }
    }
    __syncthreads();

    int quad = lane >> 4, m16 = lane & 15;
    int mrow = (wid >> 1) * 16;
    int fbase = (wid & 1) * 64;
    f32x4 acc[4];
#pragma unroll
    for (int ft = 0; ft < 4; ++ft) acc[ft] = (f32x4){0.f, 0.f, 0.f, 0.f};

    for (int kk = 0; kk < 8; ++kk) {
        int k0 = kk * 32 + quad * 8;
        bf16x8 av = *(const bf16x8*)&As[mrow + m16][k0];
#pragma unroll
        for (int ft = 0; ft < 4; ++ft) {
            int f = fbase + ft * 16 + m16;
            bf16x8 bv = *(const bf16x8*)&W2catB[(size_t)f * 256 + k0];
            acc[ft] = __builtin_amdgcn_mfma_f32_16x16x32_bf16(av, bv, acc[ft], 0, 0, 0);
        }
    }

#pragma unroll
    for (int ft = 0; ft < 4; ++ft) {
        int f = fbase + ft * 16 + m16;
        float bb = bias2[f];
#pragma unroll
        for (int r = 0; r < 4; ++r) {
            int m = mrow + quad * 4 + r;
            int node = nb + m;
            out[(size_t)node * DD + f] = acc[ft][r] + bb;
        }
    }
}

extern "C" void kernel_launch(void* const* d_in, const int* in_sizes, int n_in,
                              void* d_out, int out_size, void* d_ws, size_t ws_size,
                              hipStream_t stream) {
    const float* feat = (const float*)d_in[0];
    const int* e0 = (const int*)d_in[1];
    const int* e1 = (const int*)d_in[2];
    const int* e2 = (const int*)d_in[3];
    const float* Wl0 = (const float*)d_in[4];
    const float* bl0 = (const float*)d_in[5];
    const float* Wr0 = (const float*)d_in[6];
    const float* Wl1 = (const float*)d_in[7];
    const float* bl1 = (const float*)d_in[8];
    const float* Wr1 = (const float*)d_in[9];
    const float* Wl2 = (const float*)d_in[10];
    const float* bl2 = (const float*)d_in[11];
    const float* Wr2 = (const float*)d_in[12];
    const float* Wla = (const float*)d_in[13];
    const float* bla = (const float*)d_in[14];
    const float* Wra = (const float*)d_in[15];
    const float* Wf  = (const float*)d_in[16];
    const float* bfv = (const float*)d_in[17];
    const float* Wrf = (const float*)d_in[18];
    const float* gamma = (const float*)d_in[19];
    const float* beta  = (const float*)d_in[20];
    const float* wt    = (const float*)d_in[21];

    int* deg      = (int*)d_ws;              // 3*NN
    int* rowstart = deg + 3 * NN;            // 3*NN
    int* fillpos  = rowstart + 3 * NN;       // 3*NN
    int* csr      = fillpos + 3 * NN;        // 3*NE
    int* bsum     = csr + 3 * NE;            // 147 (pad 160)
    float* partials = (float*)(bsum + 160);  // 256*NBLK1
    float* bias1  = partials + 256 * NBLK1;  // 128
    float* bias2  = bias1 + 128;             // 128
    float* bnA    = bias2 + 128;             // 128
    float* bnB    = bnA + 128;               // 128
    unsigned short* WcatB  = (unsigned short*)(bnB + 128);   // 128*640
    unsigned short* W2catB = WcatB + 81920;                  // 128*256
    unsigned short* comb   = W2catB + 32768;                 // NN*128
    unsigned short* featB  = comb + (size_t)NN * DD;         // NN*128

    hipMemsetAsync(deg, 0, (size_t)3 * NN * sizeof(int), stream);

    feat_to_bf16<<<6250, 256, 0, stream>>>(feat, featB);
    prep_weights<<<449, 256, 0, stream>>>(Wl0, bl0, Wr0, Wl1, bl1, Wr1, Wl2, bl2, Wr2,
                                          Wla, bla, Wra, Wf, bfv, Wrf, wt,
                                          WcatB, bias1, W2catB, bias2);
    count_deg<<<3516, 256, 0, stream>>>(e0, e1, e2, deg);
    scan_local<<<147, 256, 0, stream>>>(deg, rowstart, bsum);
    scan_bsum<<<1, 64, 0, stream>>>(bsum);
    scan_fix<<<147, 256, 0, stream>>>(rowstart, fillpos, bsum);
    fill_csr<<<3516, 256, 0, stream>>>(e0, e1, e2, fillpos, csr);

    gemm1_fused<<<NBLK1, 256, 0, stream>>>(featB, deg, rowstart, csr, WcatB, bias1,
                                           comb, partials);
    bnfin<<<128, 256, 0, stream>>>(partials, gamma, beta, bnA, bnB);
    gemm2_fused<<<NBLK1, 256, 0, stream>>>(comb, deg, rowstart, csr, bnA, bnB,
                                           W2catB, bias2, (float*)d_out);
}

// Round 6
// 490.963 us; speedup vs baseline: 7.0647x; 1.3425x over previous
//
#include <hip/hip_runtime.h>

#define NN 100000
#define NE 300000
#define DD 128
#define NBLKG 782            // ceil(NN/128) gemm blocks
#define NBLKSEG 49           // ceil(NN/2048) scan blocks per segment

typedef short bf16x8 __attribute__((ext_vector_type(8)));
typedef float f32x4 __attribute__((ext_vector_type(4)));

__device__ __forceinline__ unsigned short f2b(float f) {
    union { float f; unsigned u; } c; c.f = f;
    unsigned u = c.u;
    return (unsigned short)((u + 0x7fffu + ((u >> 16) & 1u)) >> 16);
}
__device__ __forceinline__ float b2lo(unsigned u) {
    union { float f; unsigned u; } c; c.u = u << 16; return c.f;
}
__device__ __forceinline__ float b2hi(unsigned u) {
    union { float f; unsigned u; } c; c.u = u & 0xffff0000u; return c.f;
}
__device__ __forceinline__ unsigned pack2(float lo, float hi) {
    return (unsigned)f2b(lo) | ((unsigned)f2b(hi) << 16);
}

// ---------- feat -> bf16 ----------
__global__ __launch_bounds__(256) void feat_to_bf16(
    const float* __restrict__ feat, unsigned short* __restrict__ fb) {
    int gid = blockIdx.x * 256 + threadIdx.x;
    if (gid >= NN * 16) return;
    const float4* f4 = (const float4*)feat;
    float4 a = f4[gid * 2], b = f4[gid * 2 + 1];
    uint4 o;
    o.x = pack2(a.x, a.y); o.y = pack2(a.z, a.w);
    o.z = pack2(b.x, b.y); o.w = pack2(b.z, b.w);
    ((uint4*)fb)[gid] = o;
}

// ---------- weight prep ----------
__global__ __launch_bounds__(256) void prep_weights(
    const float* __restrict__ Wl0, const float* __restrict__ bl0, const float* __restrict__ Wr0,
    const float* __restrict__ Wl1, const float* __restrict__ bl1, const float* __restrict__ Wr1,
    const float* __restrict__ Wl2, const float* __restrict__ bl2, const float* __restrict__ Wr2,
    const float* __restrict__ Wla, const float* __restrict__ bla, const float* __restrict__ Wra,
    const float* __restrict__ Wf,  const float* __restrict__ bfv, const float* __restrict__ Wrf,
    const float* __restrict__ wt,
    unsigned short* __restrict__ WcatB, float* __restrict__ bias1,
    unsigned short* __restrict__ W2catB, float* __restrict__ bias2) {
    int idx = blockIdx.x * 256 + threadIdx.x;
    float w0 = wt[0], w1 = wt[1], w2 = wt[2];
    if (idx < 81920) {
        int f = idx / 640, k = idx % 640;   // [f][kcat]
        float v;
        if (k < 128)      v = w0 * Wl0[f * 128 + k];
        else if (k < 256) v = w1 * Wl1[f * 128 + (k - 128)];
        else if (k < 384) v = w2 * Wl2[f * 128 + (k - 256)];
        else if (k < 512) v = Wla[f * 128 + (k - 384)];
        else {
            int kk = k - 512;
            v = w0 * Wr0[f * 128 + kk] + w1 * Wr1[f * 128 + kk] +
                w2 * Wr2[f * 128 + kk] + Wra[f * 128 + kk];
        }
        WcatB[idx] = f2b(v);
    } else if (idx < 81920 + 32768) {
        int j = idx - 81920;
        int f = j >> 8, k = j & 255;        // [f][k], K=256
        W2catB[j] = f2b((k < 128) ? Wf[f * 128 + k] : Wrf[f * 128 + (k - 128)]);
    } else if (idx < 81920 + 32768 + 128) {
        int f = idx - (81920 + 32768);
        bias1[f] = w0 * bl0[f] + w1 * bl1[f] + w2 * bl2[f] + bla[f];
        bias2[f] = bfv[f];
    }
}

// ---------- CSR build ----------
__global__ __launch_bounds__(256) void count_deg(
    const int* __restrict__ e0, const int* __restrict__ e1, const int* __restrict__ e2,
    int* __restrict__ deg) {
    int gid = blockIdx.x * 256 + threadIdx.x;
    if (gid >= 3 * NE) return;
    int t = (gid < NE) ? 0 : ((gid < 2 * NE) ? 1 : 2);
    int i = gid - t * NE;
    const int* ep = (t == 0) ? e0 : ((t == 1) ? e1 : e2);
    atomicAdd(&deg[t * NN + ep[NE + i]], 1);
}

__global__ __launch_bounds__(256) void scan_local(
    const int* __restrict__ deg, int* __restrict__ rowstart, int* __restrict__ bsum) {
    __shared__ int sc[256];
    int b = blockIdx.x, tid = threadIdx.x;
    int seg = b / NBLKSEG, blk = b % NBLKSEG;
    int g0 = seg * NN;
    int base = blk * 2048 + tid * 8;
    int vals[8]; int tsum = 0;
#pragma unroll
    for (int j = 0; j < 8; ++j) {
        int l = base + j;
        int d = (l < NN) ? deg[g0 + l] : 0;
        vals[j] = tsum; tsum += d;
    }
    sc[tid] = tsum;
    __syncthreads();
    for (int off = 1; off < 256; off <<= 1) {
        int v = (tid >= off) ? sc[tid - off] : 0;
        __syncthreads();
        sc[tid] += v;
        __syncthreads();
    }
    int excl = sc[tid] - tsum;
#pragma unroll
    for (int j = 0; j < 8; ++j) {
        int l = base + j;
        if (l < NN) rowstart[g0 + l] = excl + vals[j];
    }
    if (tid == 255) bsum[b] = sc[255];
}

__global__ void scan_bsum(int* __restrict__ bsum) {
    int tid = threadIdx.x;
    if (tid < 3) {
        int run = 0;
        for (int b = 0; b < NBLKSEG; ++b) {
            int idx = tid * NBLKSEG + b;
            int t = bsum[idx]; bsum[idx] = run; run += t;
        }
    }
}

__global__ __launch_bounds__(256) void scan_fix(
    int* __restrict__ rowstart, int* __restrict__ fillpos, const int* __restrict__ bsum) {
    int b = blockIdx.x, tid = threadIdx.x;
    int seg = b / NBLKSEG, blk = b % NBLKSEG;
    int g0 = seg * NN;
    int base = blk * 2048 + tid * 8;
    int off = bsum[b];
#pragma unroll
    for (int j = 0; j < 8; ++j) {
        int l = base + j;
        if (l < NN) {
            int r = rowstart[g0 + l] + off;
            rowstart[g0 + l] = r;
            fillpos[g0 + l] = r;
        }
    }
}

__global__ __launch_bounds__(256) void fill_csr(
    const int* __restrict__ e0, const int* __restrict__ e1, const int* __restrict__ e2,
    int* __restrict__ fillpos, int* __restrict__ csr) {
    int gid = blockIdx.x * 256 + threadIdx.x;
    if (gid >= 3 * NE) return;
    int t = (gid < NE) ? 0 : ((gid < 2 * NE) ? 1 : 2);
    int i = gid - t * NE;
    const int* ep = (t == 0) ? e0 : ((t == 1) ? e1 : e2);
    int src = ep[i], dst = ep[NE + i];
    int p = atomicAdd(&fillpos[t * NN + dst], 1);
    csr[t * NE + p] = src;
}

// ---------- gather1: wave per node, no LDS; writes meanB[n][512] bf16 ----------
__global__ __launch_bounds__(256) void gather1(
    const unsigned short* __restrict__ featB,
    const int* __restrict__ deg, const int* __restrict__ rowstart, const int* __restrict__ csr,
    unsigned short* __restrict__ meanB) {
    int n = (blockIdx.x * 256 + threadIdx.x) >> 6;
    if (n >= NN) return;
    int lane = threadIdx.x & 63, slot = lane >> 4, fq = lane & 15;
    float aA[8] = {0.f, 0.f, 0.f, 0.f, 0.f, 0.f, 0.f, 0.f};
    int dall = 0;
#pragma unroll
    for (int t = 0; t < 3; ++t) {
        int d = deg[t * NN + n];
        int r0 = rowstart[t * NN + n];
        float ac[8] = {0.f, 0.f, 0.f, 0.f, 0.f, 0.f, 0.f, 0.f};
        for (int j = slot; j < d; j += 4) {
            int src = csr[(size_t)t * NE + r0 + j];
            uint4 v = *(const uint4*)(featB + (size_t)src * DD + fq * 8);
            ac[0] += b2lo(v.x); ac[1] += b2hi(v.x);
            ac[2] += b2lo(v.y); ac[3] += b2hi(v.y);
            ac[4] += b2lo(v.z); ac[5] += b2hi(v.z);
            ac[6] += b2lo(v.w); ac[7] += b2hi(v.w);
        }
#pragma unroll
        for (int i = 0; i < 8; ++i) {
            ac[i] += __shfl_xor(ac[i], 16);
            ac[i] += __shfl_xor(ac[i], 32);
            aA[i] += ac[i];
        }
        dall += d;
        if (slot == 0) {
            float inv = 1.0f / fmaxf((float)d, 1.0f);
            uint4 o;
            o.x = pack2(ac[0] * inv, ac[1] * inv);
            o.y = pack2(ac[2] * inv, ac[3] * inv);
            o.z = pack2(ac[4] * inv, ac[5] * inv);
            o.w = pack2(ac[6] * inv, ac[7] * inv);
            *(uint4*)(meanB + (size_t)n * 512 + t * 128 + fq * 8) = o;
        }
    }
    if (slot == 0) {
        float inv = 1.0f / fmaxf((float)dall, 1.0f);
        uint4 o;
        o.x = pack2(aA[0] * inv, aA[1] * inv);
        o.y = pack2(aA[2] * inv, aA[3] * inv);
        o.z = pack2(aA[4] * inv, aA[5] * inv);
        o.w = pack2(aA[6] * inv, aA[7] * inv);
        *(uint4*)(meanB + (size_t)n * 512 + 384 + fq * 8) = o;
    }
}

// ---------- gemm1_tile: [128 nodes x 640] @ [640 x 128] MFMA, bias+relu, BN partials ----------
__global__ __launch_bounds__(256) void gemm1_tile(
    const unsigned short* __restrict__ meanB, const unsigned short* __restrict__ featB,
    const unsigned short* __restrict__ WcatB, const float* __restrict__ bias1,
    unsigned short* __restrict__ comb, float* __restrict__ partials) {
    __shared__ unsigned short ABs[65536 / 2];   // As = [0,32768), Bs = [32768,65536) shorts... (bytes/2)
    unsigned short* As = ABs;                   // fragment-major: ((s*128+row)*4+q)*8
    unsigned short* Bs = ABs + 16384;           // 16384 shorts = 32 KB
    int tid = threadIdx.x;
    int wid = tid >> 6, lane = tid & 63;
    int quad = lane >> 4, m16 = lane & 15;
    int nb = blockIdx.x * 128;
    int mb = (wid & 1) * 64, fb = (wid >> 1) * 64;
    f32x4 acc[4][4];
#pragma unroll
    for (int mi = 0; mi < 4; ++mi)
#pragma unroll
        for (int fi = 0; fi < 4; ++fi) acc[mi][fi] = (f32x4){0.f, 0.f, 0.f, 0.f};

    for (int kc = 0; kc < 5; ++kc) {
        __syncthreads();
#pragma unroll
        for (int it = 0; it < 8; ++it) {
            int idx = it * 256 + tid;
            int row = idx >> 4, chunk = idx & 15;
            int s = chunk >> 2, q = chunk & 3;
            int gr = min(nb + row, NN - 1);
            uint4 v = (kc < 4)
                ? *(const uint4*)(meanB + (size_t)gr * 512 + kc * 128 + chunk * 8)
                : *(const uint4*)(featB + (size_t)gr * DD + chunk * 8);
            *(uint4*)&As[(((s * 128 + row) * 4) + q) * 8] = v;
        }
#pragma unroll
        for (int it = 0; it < 8; ++it) {
            int idx = it * 256 + tid;
            int f = idx >> 4, chunk = idx & 15;
            int s = chunk >> 2, q = chunk & 3;
            uint4 v = *(const uint4*)(WcatB + (size_t)f * 640 + kc * 128 + chunk * 8);
            *(uint4*)&Bs[(((s * 128 + f) * 4) + q) * 8] = v;
        }
        __syncthreads();
#pragma unroll
        for (int s = 0; s < 4; ++s) {
            bf16x8 av[4], bv[4];
#pragma unroll
            for (int mi = 0; mi < 4; ++mi)
                av[mi] = *(const bf16x8*)&As[(((s * 128 + mb + mi * 16 + m16) * 4) + quad) * 8];
#pragma unroll
            for (int fi = 0; fi < 4; ++fi)
                bv[fi] = *(const bf16x8*)&Bs[(((s * 128 + fb + fi * 16 + m16) * 4) + quad) * 8];
#pragma unroll
            for (int mi = 0; mi < 4; ++mi)
#pragma unroll
                for (int fi = 0; fi < 4; ++fi)
                    acc[mi][fi] = __builtin_amdgcn_mfma_f32_16x16x32_bf16(av[mi], bv[fi], acc[mi][fi], 0, 0, 0);
        }
    }
    __syncthreads();    // all waves done reading LDS; reuse for BN partials
    float* bnS = (float*)ABs;
    float* bnQ = bnS + 128;
    if (tid < 128) { bnS[tid] = 0.f; bnQ[tid] = 0.f; }
    __syncthreads();
#pragma unroll
    for (int fi = 0; fi < 4; ++fi) {
        int f = fb + fi * 16 + m16;
        float bb = bias1[f];
        float s = 0.f, q = 0.f;
#pragma unroll
        for (int mi = 0; mi < 4; ++mi) {
#pragma unroll
            for (int r = 0; r < 4; ++r) {
                int row = nb + mb + mi * 16 + quad * 4 + r;
                float v = fmaxf(acc[mi][fi][r] + bb, 0.f);
                if (row < NN) {
                    s += v; q += v * v;
                    comb[(size_t)row * DD + f] = f2b(v);
                }
            }
        }
        atomicAdd(&bnS[f], s);
        atomicAdd(&bnQ[f], q);
    }
    __syncthreads();
    if (tid < 128) {
        partials[(size_t)tid * NBLKG + blockIdx.x] = bnS[tid];
        partials[(size_t)(128 + tid) * NBLKG + blockIdx.x] = bnQ[tid];
    }
}

// ---------- BN finalize ----------
__global__ __launch_bounds__(256) void bnfin(
    const float* __restrict__ partials,
    const float* __restrict__ gamma, const float* __restrict__ beta,
    float* __restrict__ bnA, float* __restrict__ bnB) {
    __shared__ float rs[256], rq[256];
    int f = blockIdx.x, tid = threadIdx.x;
    float s = 0.f, q = 0.f;
    for (int r = tid; r < NBLKG; r += 256) {
        s += partials[(size_t)f * NBLKG + r];
        q += partials[(size_t)(128 + f) * NBLKG + r];
    }
    rs[tid] = s; rq[tid] = q;
    __syncthreads();
    for (int off = 128; off > 0; off >>= 1) {
        if (tid < off) { rs[tid] += rs[tid + off]; rq[tid] += rq[tid + off]; }
        __syncthreads();
    }
    if (tid == 0) {
        float mu = rs[0] / (float)NN;
        float var = fmaxf(rq[0] / (float)NN - mu * mu, 0.f);
        float a = gamma[f] * rsqrtf(var + 1e-5f);
        bnA[f] = a;
        bnB[f] = beta[f] - mu * a;
    }
}

// ---------- gather2: wave per node; mean of BN(comb) rows -> meanC[n][128] bf16 ----------
__global__ __launch_bounds__(256) void gather2(
    const unsigned short* __restrict__ comb,
    const int* __restrict__ deg, const int* __restrict__ rowstart, const int* __restrict__ csr,
    const float* __restrict__ bnA, const float* __restrict__ bnB,
    unsigned short* __restrict__ meanC) {
    int n = (blockIdx.x * 256 + threadIdx.x) >> 6;
    if (n >= NN) return;
    int lane = threadIdx.x & 63, slot = lane >> 4, fq = lane & 15;
    float ac[8] = {0.f, 0.f, 0.f, 0.f, 0.f, 0.f, 0.f, 0.f};
    int dall = 0;
#pragma unroll
    for (int t = 0; t < 3; ++t) {
        int d = deg[t * NN + n];
        int r0 = rowstart[t * NN + n];
        for (int j = slot; j < d; j += 4) {
            int src = csr[(size_t)t * NE + r0 + j];
            uint4 v = *(const uint4*)(comb + (size_t)src * DD + fq * 8);
            ac[0] += b2lo(v.x); ac[1] += b2hi(v.x);
            ac[2] += b2lo(v.y); ac[3] += b2hi(v.y);
            ac[4] += b2lo(v.z); ac[5] += b2hi(v.z);
            ac[6] += b2lo(v.w); ac[7] += b2hi(v.w);
        }
        dall += d;
    }
#pragma unroll
    for (int i = 0; i < 8; ++i) {
        ac[i] += __shfl_xor(ac[i], 16);
        ac[i] += __shfl_xor(ac[i], 32);
    }
    if (slot == 0) {
        float v[8] = {0.f, 0.f, 0.f, 0.f, 0.f, 0.f, 0.f, 0.f};
        if (dall > 0) {
            float inv = 1.0f / (float)dall;
            float4 a0 = *(const float4*)&bnA[fq * 8], a1 = *(const float4*)&bnA[fq * 8 + 4];
            float4 b0 = *(const float4*)&bnB[fq * 8], b1 = *(const float4*)&bnB[fq * 8 + 4];
            v[0] = a0.x * (ac[0] * inv) + b0.x; v[1] = a0.y * (ac[1] * inv) + b0.y;
            v[2] = a0.z * (ac[2] * inv) + b0.z; v[3] = a0.w * (ac[3] * inv) + b0.w;
            v[4] = a1.x * (ac[4] * inv) + b1.x; v[5] = a1.y * (ac[5] * inv) + b1.y;
            v[6] = a1.z * (ac[6] * inv) + b1.z; v[7] = a1.w * (ac[7] * inv) + b1.w;
        }
        uint4 o;
        o.x = pack2(v[0], v[1]); o.y = pack2(v[2], v[3]);
        o.z = pack2(v[4], v[5]); o.w = pack2(v[6], v[7]);
        *(uint4*)(meanC + (size_t)n * DD + fq * 8) = o;
    }
}

// ---------- gemm2_tile: [128 x 256] @ [256 x 128], fp32 out ----------
__global__ __launch_bounds__(256) void gemm2_tile(
    const unsigned short* __restrict__ meanC, const unsigned short* __restrict__ comb,
    const float* __restrict__ bnA, const float* __restrict__ bnB,
    const unsigned short* __restrict__ W2catB, const float* __restrict__ bias2,
    float* __restrict__ out) {
    __shared__ unsigned short ABs[65536 / 2];
    unsigned short* As = ABs;
    unsigned short* Bs = ABs + 16384;
    int tid = threadIdx.x;
    int wid = tid >> 6, lane = tid & 63;
    int quad = lane >> 4, m16 = lane & 15;
    int nb = blockIdx.x * 128;
    int mb = (wid & 1) * 64, fb = (wid >> 1) * 64;
    f32x4 acc[4][4];
#pragma unroll
    for (int mi = 0; mi < 4; ++mi)
#pragma unroll
        for (int fi = 0; fi < 4; ++fi) acc[mi][fi] = (f32x4){0.f, 0.f, 0.f, 0.f};

    for (int kc = 0; kc < 2; ++kc) {
        __syncthreads();
#pragma unroll
        for (int it = 0; it < 8; ++it) {
            int idx = it * 256 + tid;
            int row = idx >> 4, chunk = idx & 15;
            int s = chunk >> 2, q = chunk & 3;
            int gr = min(nb + row, NN - 1);
            uint4 v;
            if (kc == 0) {
                v = *(const uint4*)(meanC + (size_t)gr * DD + chunk * 8);
            } else {
                uint4 c4 = *(const uint4*)(comb + (size_t)gr * DD + chunk * 8);
                int cb = chunk * 8;
                float4 a0 = *(const float4*)&bnA[cb], a1 = *(const float4*)&bnA[cb + 4];
                float4 b0 = *(const float4*)&bnB[cb], b1 = *(const float4*)&bnB[cb + 4];
                v.x = pack2(a0.x * b2lo(c4.x) + b0.x, a0.y * b2hi(c4.x) + b0.y);
                v.y = pack2(a0.z * b2lo(c4.y) + b0.z, a0.w * b2hi(c4.y) + b0.w);
                v.z = pack2(a1.x * b2lo(c4.z) + b1.x, a1.y * b2hi(c4.z) + b1.y);
                v.w = pack2(a1.z * b2lo(c4.w) + b1.z, a1.w * b2hi(c4.w) + b1.w);
            }
            *(uint4*)&As[(((s * 128 + row) * 4) + q) * 8] = v;
        }
#pragma unroll
        for (int it = 0; it < 8; ++it) {
            int idx = it * 256 + tid;
            int f = idx >> 4, chunk = idx & 15;
            int s = chunk >> 2, q = chunk & 3;
            uint4 v = *(const uint4*)(W2catB + (size_t)f * 256 + kc * 128 + chunk * 8);
            *(uint4*)&Bs[(((s * 128 + f) * 4) + q) * 8] = v;
        }
        __syncthreads();
#pragma unroll
        for (int s = 0; s < 4; ++s) {
            bf16x8 av[4], bv[4];
#pragma unroll
            for (int mi = 0; mi < 4; ++mi)
                av[mi] = *(const bf16x8*)&As[(((s * 128 + mb + mi * 16 + m16) * 4) + quad) * 8];
#pragma unroll
            for (int fi = 0; fi < 4; ++fi)
                bv[fi] = *(const bf16x8*)&Bs[(((s * 128 + fb + fi * 16 + m16) * 4) + quad) * 8];
#pragma unroll
            for (int mi = 0; mi < 4; ++mi)
#pragma unroll
                for (int fi = 0; fi < 4; ++fi)
                    acc[mi][fi] = __builtin_amdgcn_mfma_f32_16x16x32_bf16(av[mi], bv[fi], acc[mi][fi], 0, 0, 0);
        }
    }
#pragma unroll
    for (int fi = 0; fi < 4; ++fi) {
        int f = fb + fi * 16 + m16;
        float bb = bias2[f];
#pragma unroll
        for (int mi = 0; mi < 4; ++mi) {
#pragma unroll
            for (int r = 0; r < 4; ++r) {
                int row = nb + mb + mi * 16 + quad * 4 + r;
                if (row < NN) out[(size_t)row * DD + f] = acc[mi][fi][r] + bb;
            }
        }
    }
}

extern "C" void kernel_launch(void* const* d_in, const int* in_sizes, int n_in,
                              void* d_out, int out_size, void* d_ws, size_t ws_size,
                              hipStream_t stream) {
    const float* feat = (const float*)d_in[0];
    const int* e0 = (const int*)d_in[1];
    const int* e1 = (const int*)d_in[2];
    const int* e2 = (const int*)d_in[3];
    const float* Wl0 = (const float*)d_in[4];
    const float* bl0 = (const float*)d_in[5];
    const float* Wr0 = (const float*)d_in[6];
    const float* Wl1 = (const float*)d_in[7];
    const float* bl1 = (const float*)d_in[8];
    const float* Wr1 = (const float*)d_in[9];
    const float* Wl2 = (const float*)d_in[10];
    const float* bl2 = (const float*)d_in[11];
    const float* Wr2 = (const float*)d_in[12];
    const float* Wla = (const float*)d_in[13];
    const float* bla = (const float*)d_in[14];
    const float* Wra = (const float*)d_in[15];
    const float* Wf  = (const float*)d_in[16];
    const float* bfv = (const float*)d_in[17];
    const float* Wrf = (const float*)d_in[18];
    const float* gamma = (const float*)d_in[19];
    const float* beta  = (const float*)d_in[20];
    const float* wt    = (const float*)d_in[21];

    int* deg      = (int*)d_ws;              // 3*NN
    int* rowstart = deg + 3 * NN;            // 3*NN
    int* fillpos  = rowstart + 3 * NN;       // 3*NN
    int* csr      = fillpos + 3 * NN;        // 3*NE
    int* bsum     = csr + 3 * NE;            // 147 (pad 160)
    float* partials = (float*)(bsum + 160);  // 256*NBLKG
    float* bias1  = partials + 256 * NBLKG;  // 128
    float* bias2  = bias1 + 128;             // 128
    float* bnA    = bias2 + 128;             // 128
    float* bnB    = bnA + 128;               // 128
    unsigned short* WcatB  = (unsigned short*)(bnB + 128);   // 128*640
    unsigned short* W2catB = WcatB + 81920;                  // 128*256
    unsigned short* comb   = W2catB + 32768;                 // NN*128
    unsigned short* featB  = comb + (size_t)NN * DD;         // NN*128
    unsigned short* meanB  = featB + (size_t)NN * DD;        // NN*512
    unsigned short* meanC  = meanB + (size_t)NN * 512;       // NN*128

    hipMemsetAsync(deg, 0, (size_t)3 * NN * sizeof(int), stream);

    feat_to_bf16<<<6250, 256, 0, stream>>>(feat, featB);
    prep_weights<<<449, 256, 0, stream>>>(Wl0, bl0, Wr0, Wl1, bl1, Wr1, Wl2, bl2, Wr2,
                                          Wla, bla, Wra, Wf, bfv, Wrf, wt,
                                          WcatB, bias1, W2catB, bias2);
    count_deg<<<3516, 256, 0, stream>>>(e0, e1, e2, deg);
    scan_local<<<147, 256, 0, stream>>>(deg, rowstart, bsum);
    scan_bsum<<<1, 64, 0, stream>>>(bsum);
    scan_fix<<<147, 256, 0, stream>>>(rowstart, fillpos, bsum);
    fill_csr<<<3516, 256, 0, stream>>>(e0, e1, e2, fillpos, csr);

    gather1<<<25000, 256, 0, stream>>>(featB, deg, rowstart, csr, meanB);
    gemm1_tile<<<NBLKG, 256, 0, stream>>>(meanB, featB, WcatB, bias1, comb, partials);
    bnfin<<<128, 256, 0, stream>>>(partials, gamma, beta, bnA, bnB);
    gather2<<<25000, 256, 0, stream>>>(comb, deg, rowstart, csr, bnA, bnB, meanC);
    gemm2_tile<<<NBLKG, 256, 0, stream>>>(meanC, comb, bnA, bnB, W2catB, bias2,
                                          (float*)d_out);
}